// Round 1
// baseline (58.524 us; speedup 1.0000x reference)
//
#include <hip/hip_runtime.h>
#include <math.h>

#define NCOL 22
#define NEMB 12
#define D 64
#define BB 2048
#define NPAIR (NCOL*NCOL)   // 484
#define PPW 121             // pairs per wave (484/4)

// ---------------- kernel 1: trans lookup table (22*12*64 = 16896 values) ---
__global__ __launch_bounds__(256) void k_trans(const float* __restrict__ tables,
        const float* __restrict__ w1, const float* __restrict__ b1,
        const float* __restrict__ w2, const float* __restrict__ b2,
        float* __restrict__ trans) {
    int idx = blockIdx.x * 256 + threadIdx.x;      // exactly 66*256 = 16896
    float x = tables[idx];
    float acc = b2[0];
    #pragma unroll
    for (int h = 0; h < 8; ++h)
        acc = fmaf(tanhf(fmaf(x, w1[h], b1[h])), w2[h], acc);
    trans[idx] = acc;
}

// ---------------- kernel 2: folded linear weights Wlin[i][o][d] ------------
__global__ __launch_bounds__(256) void k_wlin(const float* __restrict__ W_ops,
        const float* __restrict__ W_concat, const float* __restrict__ aw,
        float* __restrict__ wlin) {
    int idx = blockIdx.x * 256 + threadIdx.x;      // exactly 11*256 = 2816
    int d = idx & 63; int o = (idx >> 6) & 1; int i = idx >> 7;
    float a0 = aw[0], a2 = aw[2], a3 = aw[3], a4 = aw[4];
    const float* Wp   = W_ops;
    const float* Wmax = W_ops + 2 * NPAIR * 2 * D;
    const float* Wmin = W_ops + 3 * NPAIR * 2 * D;
    float lp = 0.f, lc = 0.f, lmm = 0.f;
    for (int j = 0; j < NCOL; ++j) {
        int ij = ((i * NCOL + j) * 2 + o) * D + d;
        int ji = ((j * NCOL + i) * 2 + o) * D + d;
        lp += Wp[ij] + Wp[ji];
        lc += W_concat[((i * NCOL + j) * 2 + o) * 2 * D + d]
            + W_concat[((j * NCOL + i) * 2 + o) * 2 * D + D + d];
        lmm += (a2 * Wmax[ij] + a3 * Wmin[ij]) + (a2 * Wmax[ji] + a3 * Wmin[ji]);
    }
    wlin[idx] = a0 * lp + a4 * lc + 0.5f * lmm;
}

// ---------------- kernel 3: pair weights pw[ij][d] = (wm0,wm1,wa0,wa1) -----
__global__ __launch_bounds__(256) void k_pair(const float* __restrict__ W_ops,
        const float* __restrict__ aw, float4* __restrict__ pw) {
    int idx = blockIdx.x * 256 + threadIdx.x;      // exactly 121*256 = 30976
    int d = idx & 63; int ij = idx >> 6;
    float a1 = aw[1], a2 = aw[2], a3 = aw[3];
    const float* Wm   = W_ops + 1 * NPAIR * 2 * D;
    const float* Wmax = W_ops + 2 * NPAIR * 2 * D;
    const float* Wmin = W_ops + 3 * NPAIR * 2 * D;
    int b0 = (ij * 2 + 0) * D + d;
    int b1 = (ij * 2 + 1) * D + d;
    float4 v;
    v.x = a1 * Wm[b0];
    v.y = a1 * Wm[b1];
    v.z = 0.5f * (a2 * Wmax[b0] - a3 * Wmin[b0]);
    v.w = 0.5f * (a2 * Wmax[b1] - a3 * Wmin[b1]);
    pw[idx] = v;
}

// ---------------- kernel 4: col norms via histogram ------------------------
__global__ __launch_bounds__(256) void k_regs(const int* __restrict__ features,
        const float* __restrict__ tables, float* __restrict__ colnorm) {
    __shared__ int hist[NEMB];
    __shared__ float partials[4];
    int i = blockIdx.x; int tid = threadIdx.x;
    if (tid < NEMB) hist[tid] = 0;
    __syncthreads();
    for (int k = tid; k < BB; k += 256)
        atomicAdd(&hist[features[i * BB + k]], 1);
    __syncthreads();
    float part = 0.f;
    for (int k = tid; k < NEMB * D; k += 256) {
        int e = k >> 6, d = k & 63;
        float v = tables[(i * NEMB + e) * D + d];
        part += (float)hist[e] * v * v;
    }
    #pragma unroll
    for (int m = 32; m; m >>= 1) part += __shfl_xor(part, m);
    if ((tid & 63) == 0) partials[tid >> 6] = part;
    __syncthreads();
    if (tid == 0)
        colnorm[i] = sqrtf(partials[0] + partials[1] + partials[2] + partials[3]);
}

// ---------------- kernel 5: main — 8 b's per block, pairs split by wave ----
#define QSTEP(TI, TJ, A0, A1) \
    { float pp_ = (TI) * (TJ); float dd_ = fabsf((TI) - (TJ)); \
      (A0) = fmaf(pp_, w4.x, fmaf(dd_, w4.z, (A0))); \
      (A1) = fmaf(pp_, w4.y, fmaf(dd_, w4.w, (A1))); }

#define LSTEP(T, A0, A1) \
    { (A0) = fmaf((T), wl0, (A0)); (A1) = fmaf((T), wl1, (A1)); }

__global__ __launch_bounds__(256) void k_main(const int* __restrict__ features,
        const float* __restrict__ trans, const float* __restrict__ wlin,
        const float4* __restrict__ pw, const float* __restrict__ colnorm,
        float* __restrict__ out) {
    __shared__ int feat[NCOL][8];
    __shared__ float tl[2][NCOL][D][4];   // [qgroup][i][d][q%4] -> float4/lane
    __shared__ float red[4][16];
    int tid = threadIdx.x;
    int b0 = blockIdx.x * 8;

    if (tid < NCOL * 8) {
        int i = tid >> 3, q = tid & 7;
        feat[i][q] = features[i * BB + b0 + q];
    }
    __syncthreads();
    for (int e = tid; e < NCOL * 8 * D; e += 256) {
        int d = e & 63; int row = e >> 6; int i = row >> 3; int q = row & 7;
        tl[q >> 2][i][d][q & 3] = trans[(i * NEMB + feat[i][q]) * D + d];
    }
    __syncthreads();

    int w = tid >> 6, lane = tid & 63;
    float4 a0A = {0,0,0,0}, a0B = {0,0,0,0}, a1A = {0,0,0,0}, a1B = {0,0,0,0};

    int ij0 = w * PPW;
    int i = ij0 / NCOL, j = ij0 % NCOL;
    const float4* pwp = pw + ij0 * D + lane;
    for (int p = 0; p < PPW; ++p) {
        float4 w4 = *pwp; pwp += D;
        float4 ta = *(const float4*)&tl[0][i][lane][0];
        float4 tc = *(const float4*)&tl[1][i][lane][0];
        float4 tb = *(const float4*)&tl[0][j][lane][0];
        float4 te = *(const float4*)&tl[1][j][lane][0];
        QSTEP(ta.x, tb.x, a0A.x, a1A.x)
        QSTEP(ta.y, tb.y, a0A.y, a1A.y)
        QSTEP(ta.z, tb.z, a0A.z, a1A.z)
        QSTEP(ta.w, tb.w, a0A.w, a1A.w)
        QSTEP(tc.x, te.x, a0B.x, a1B.x)
        QSTEP(tc.y, te.y, a0B.y, a1B.y)
        QSTEP(tc.z, te.z, a0B.z, a1B.z)
        QSTEP(tc.w, te.w, a0B.w, a1B.w)
        if (++j == NCOL) { j = 0; ++i; }
    }

    if (w == 0) {   // linear term once per block
        for (int ii = 0; ii < NCOL; ++ii) {
            float wl0 = wlin[(ii * 2 + 0) * D + lane];
            float wl1 = wlin[(ii * 2 + 1) * D + lane];
            float4 tA = *(const float4*)&tl[0][ii][lane][0];
            float4 tB = *(const float4*)&tl[1][ii][lane][0];
            LSTEP(tA.x, a0A.x, a1A.x)
            LSTEP(tA.y, a0A.y, a1A.y)
            LSTEP(tA.z, a0A.z, a1A.z)
            LSTEP(tA.w, a0A.w, a1A.w)
            LSTEP(tB.x, a0B.x, a1B.x)
            LSTEP(tB.y, a0B.y, a1B.y)
            LSTEP(tB.z, a0B.z, a1B.z)
            LSTEP(tB.w, a0B.w, a1B.w)
        }
    }

    // lane reduce over d (16 independent values, k = q*2 + o)
    float vals[16] = { a0A.x, a1A.x, a0A.y, a1A.y, a0A.z, a1A.z, a0A.w, a1A.w,
                       a0B.x, a1B.x, a0B.y, a1B.y, a0B.z, a1B.z, a0B.w, a1B.w };
    #pragma unroll
    for (int m = 32; m; m >>= 1) {
        #pragma unroll
        for (int k = 0; k < 16; ++k) vals[k] += __shfl_xor(vals[k], m);
    }
    if (lane == 0) {
        #pragma unroll
        for (int k = 0; k < 16; ++k) red[w][k] = vals[k];
    }
    __syncthreads();
    if (tid < 16)
        out[b0 * 2 + tid] = red[0][tid] + red[1][tid] + red[2][tid] + red[3][tid];

    if (blockIdx.x == 0 && tid == 64) {
        float s = 0.f;
        for (int c = 0; c < NCOL; ++c) s += colnorm[c];
        out[BB * 2] = 0.001f * (2.0f * NCOL) * s;
    }
}

extern "C" void kernel_launch(void* const* d_in, const int* in_sizes, int n_in,
                              void* d_out, int out_size, void* d_ws, size_t ws_size,
                              hipStream_t stream) {
    const int*   features = (const int*)d_in[0];
    const float* tables   = (const float*)d_in[1];
    const float* w1       = (const float*)d_in[2];
    const float* b1       = (const float*)d_in[3];
    const float* w2       = (const float*)d_in[4];
    const float* b2       = (const float*)d_in[5];
    const float* W_ops    = (const float*)d_in[6];
    const float* W_concat = (const float*)d_in[7];
    const float* aw       = (const float*)d_in[8];
    float* out = (float*)d_out;
    float* ws  = (float*)d_ws;

    float*  trans   = ws;                        // 16896 f
    float*  wlin    = ws + 16896;                // 2816 f
    float4* pwv     = (float4*)(ws + 19712);     // 123904 f (16B aligned)
    float*  colnorm = ws + 19712 + 123904;       // 22 f

    k_trans<<<dim3(66),  dim3(256), 0, stream>>>(tables, w1, b1, w2, b2, trans);
    k_wlin <<<dim3(11),  dim3(256), 0, stream>>>(W_ops, W_concat, aw, wlin);
    k_pair <<<dim3(121), dim3(256), 0, stream>>>(W_ops, aw, pwv);
    k_regs <<<dim3(NCOL),dim3(256), 0, stream>>>(features, tables, colnorm);
    k_main <<<dim3(BB/8),dim3(256), 0, stream>>>(features, trans, wlin, pwv, colnorm, out);
}

// Round 2
// 37.904 us; speedup vs baseline: 1.5440x; 1.5440x over previous
//
#include <hip/hip_runtime.h>
#include <math.h>

#define NCOL 22
#define NEMB 12
#define D 64
#define BB 2048
#define NPAIR (NCOL*NCOL)   // 484
#define REGC 0.001f

// ---------------------------------------------------------------------------
// k_ptab: blocks 0..483 build the per-pair (ei,ej) table; blocks 484..505
// compute column norms and atomically accumulate the reg scalar into out[4096].
// ptab[pair][ei*12+ej] = (o0, o1) contribution of that pair for that combo,
// with the folded linear term added on diagonal pairs (where ei==ej always).
// ---------------------------------------------------------------------------
__global__ __launch_bounds__(256) void k_ptab(
    const int* __restrict__ features,
    const float* __restrict__ tables,
    const float* __restrict__ w1, const float* __restrict__ b1,
    const float* __restrict__ w2, const float* __restrict__ b2,
    const float* __restrict__ W_ops, const float* __restrict__ W_concat,
    const float* __restrict__ aw,
    float2* __restrict__ ptab, float* __restrict__ out)
{
    int bid = blockIdx.x;
    int tid = threadIdx.x;

    if (bid >= NPAIR) {                       // ---- colnorm / regs blocks ----
        int i = bid - NPAIR;
        __shared__ int hist[NEMB];
        __shared__ float parts[4];
        if (tid < NEMB) hist[tid] = 0;
        __syncthreads();
        for (int k = tid; k < BB; k += 256)
            atomicAdd(&hist[features[i * BB + k]], 1);
        __syncthreads();
        float part = 0.f;
        for (int k = tid; k < NEMB * D; k += 256) {
            int e = k >> 6;
            float v = tables[i * NEMB * D + k];
            part += (float)hist[e] * v * v;
        }
        #pragma unroll
        for (int m = 32; m; m >>= 1) part += __shfl_xor(part, m);
        if ((tid & 63) == 0) parts[tid >> 6] = part;
        __syncthreads();
        if (tid == 0) {
            float cn = sqrtf(parts[0] + parts[1] + parts[2] + parts[3]);
            atomicAdd(&out[BB * 2], REGC * (2.0f * NCOL) * cn);
        }
        return;
    }

    // ---- pair-table blocks ----
    int i = bid / NCOL, j = bid % NCOL;
    __shared__ float ti[NEMB][D + 1];     // +1 pad: combo reads hit 12 banks
    __shared__ float tj[NEMB][D + 1];
    __shared__ float4 w4s[D];
    __shared__ float wl[2][D];
    __shared__ float lt[NEMB][2];

    float a0 = aw[0], a1 = aw[1], a2 = aw[2], a3 = aw[3], a4 = aw[4];
    float b2v = b2[0];

    // stage trans rows i and j (12x64 each), computed inline from tables+MLP
    for (int k = tid; k < NEMB * D; k += 256) {
        int e = k >> 6, d = k & 63;
        float x = tables[i * NEMB * D + k];
        float acc = b2v;
        #pragma unroll
        for (int h = 0; h < 8; ++h)
            acc = fmaf(tanhf(fmaf(x, w1[h], b1[h])), w2[h], acc);
        ti[e][d] = acc;
        float y = tables[j * NEMB * D + k];
        float acc2 = b2v;
        #pragma unroll
        for (int h = 0; h < 8; ++h)
            acc2 = fmaf(tanhf(fmaf(y, w1[h], b1[h])), w2[h], acc2);
        tj[e][d] = acc2;
    }

    // stage pair weights: wm (o0,o1), wabs (o0,o1)
    const float* Wm   = W_ops + 1 * NPAIR * 2 * D;
    const float* Wmax = W_ops + 2 * NPAIR * 2 * D;
    const float* Wmin = W_ops + 3 * NPAIR * 2 * D;
    if (tid < D) {
        int d = tid;
        int i0 = (bid * 2 + 0) * D + d;
        int i1 = (bid * 2 + 1) * D + d;
        float4 v;
        v.x = a1 * Wm[i0];
        v.y = a1 * Wm[i1];
        v.z = 0.5f * (a2 * Wmax[i0] - a3 * Wmin[i0]);
        v.w = 0.5f * (a2 * Wmax[i1] - a3 * Wmin[i1]);
        w4s[d] = v;
    }

    // diagonal blocks also build the folded linear weight wlin[o][d]
    if (i == j && tid < 128) {
        int o = tid >> 6, d = tid & 63;
        const float* Wp = W_ops;
        float lp = 0.f, lc = 0.f, lmm = 0.f;
        #pragma unroll
        for (int jj = 0; jj < NCOL; ++jj) {
            int ij = ((i * NCOL + jj) * 2 + o) * D + d;
            int ji = ((jj * NCOL + i) * 2 + o) * D + d;
            lp += Wp[ij] + Wp[ji];
            lc += W_concat[((i * NCOL + jj) * 2 + o) * 2 * D + d]
                + W_concat[((jj * NCOL + i) * 2 + o) * 2 * D + D + d];
            lmm += a2 * (Wmax[ij] + Wmax[ji]) + a3 * (Wmin[ij] + Wmin[ji]);
        }
        wl[o][d] = a0 * lp + a4 * lc + 0.5f * lmm;
    }
    __syncthreads();

    // diagonal: lin table lt[e][o] = sum_d t[e][d] * wl[o][d]
    if (i == j && tid < NEMB) {
        float l0 = 0.f, l1 = 0.f;
        #pragma unroll
        for (int d = 0; d < D; ++d) {
            float t = ti[tid][d];
            l0 = fmaf(t, wl[0][d], l0);
            l1 = fmaf(t, wl[1][d], l1);
        }
        lt[tid][0] = l0; lt[tid][1] = l1;
    }
    __syncthreads();

    // 144 combos: thread c -> (ei, ej)
    if (tid < NEMB * NEMB) {
        int ei = tid / NEMB, ej = tid - ei * NEMB;
        float r0 = 0.f, r1 = 0.f;
        #pragma unroll
        for (int d = 0; d < D; ++d) {
            float a = ti[ei][d], b = tj[ej][d];
            float4 w4 = w4s[d];                 // uniform -> broadcast
            float pp = a * b;
            float dd = fabsf(a - b);
            r0 = fmaf(pp, w4.x, fmaf(dd, w4.z, r0));
            r1 = fmaf(pp, w4.y, fmaf(dd, w4.w, r1));
        }
        if (i == j && ei == ej) { r0 += lt[ei][0]; r1 += lt[ei][1]; }
        ptab[bid * 144 + tid] = make_float2(r0, r1);
    }
}

// ---------------------------------------------------------------------------
// k_gather: 32 blocks x 256. Block owns 64 b's (lane = b); its 4 waves each
// sum 121 pairs via table lookups, then LDS-reduce. No fp atomics on out[0..].
// ---------------------------------------------------------------------------
__global__ __launch_bounds__(256) void k_gather(const int* __restrict__ features,
        const float2* __restrict__ ptab, float* __restrict__ out)
{
    __shared__ int fs[NCOL][64];
    __shared__ float red[4][64][2];
    int tid = threadIdx.x;
    int w = tid >> 6, lane = tid & 63;
    int b0 = blockIdx.x * 64;

    for (int k = tid; k < NCOL * 64; k += 256) {
        int i = k >> 6, l = k & 63;
        fs[i][l] = features[i * BB + b0 + l];
    }
    __syncthreads();

    float acc0 = 0.f, acc1 = 0.f;
    int pbeg = w * 121, pend = pbeg + 121;
    #pragma unroll 8
    for (int p = pbeg; p < pend; ++p) {
        int i = (p * 2979) >> 16;     // exact p/22 for p < 484
        int j = p - i * NCOL;
        int ei = fs[i][lane];
        int ej = fs[j][lane];
        float2 v = ptab[p * 144 + ei * NEMB + ej];
        acc0 += v.x; acc1 += v.y;
    }
    red[w][lane][0] = acc0;
    red[w][lane][1] = acc1;
    __syncthreads();
    if (tid < 128) {
        int l = tid >> 1, o = tid & 1;
        out[(b0 + l) * 2 + o] = red[0][l][o] + red[1][l][o]
                              + red[2][l][o] + red[3][l][o];
    }
}

extern "C" void kernel_launch(void* const* d_in, const int* in_sizes, int n_in,
                              void* d_out, int out_size, void* d_ws, size_t ws_size,
                              hipStream_t stream) {
    const int*   features = (const int*)d_in[0];
    const float* tables   = (const float*)d_in[1];
    const float* w1       = (const float*)d_in[2];
    const float* b1       = (const float*)d_in[3];
    const float* w2       = (const float*)d_in[4];
    const float* b2       = (const float*)d_in[5];
    const float* W_ops    = (const float*)d_in[6];
    const float* W_concat = (const float*)d_in[7];
    const float* aw       = (const float*)d_in[8];
    float* out = (float*)d_out;
    float2* ptab = (float2*)d_ws;    // 484*144 float2 = 557,568 B

    // zero out (regs is accumulated atomically; inferences overwritten anyway)
    hipMemsetAsync(out, 0, (size_t)out_size * sizeof(float), stream);

    k_ptab  <<<dim3(NPAIR + NCOL), dim3(256), 0, stream>>>(
        features, tables, w1, b1, w2, b2, W_ops, W_concat, aw, ptab, out);
    k_gather<<<dim3(BB / 64), dim3(256), 0, stream>>>(features, ptab, out);
}

// Round 3
// 34.396 us; speedup vs baseline: 1.7015x; 1.1020x over previous
//
#include <hip/hip_runtime.h>
#include <math.h>

#define NCOL 22
#define NEMB 12
#define D 64
#define BB 2048
#define NPAIR (NCOL*NCOL)   // 484
#define REGC 0.001f

// ---------------------------------------------------------------------------
// k_ptab: blocks 0..483 build the per-pair (ei,ej) combo table.
// Block 484 computes all 22 column norms and writes out[4096] (reg scalar).
// ptab[pair][ei*12+ej] = (o0,o1) contribution of that pair for that combo,
// with the folded linear term added on diagonal pairs (where ei==ej always).
// ---------------------------------------------------------------------------
__global__ __launch_bounds__(256) void k_ptab(
    const int* __restrict__ features,
    const float* __restrict__ tables,
    const float* __restrict__ w1, const float* __restrict__ b1,
    const float* __restrict__ w2, const float* __restrict__ b2,
    const float* __restrict__ W_ops, const float* __restrict__ W_concat,
    const float* __restrict__ aw,
    float2* __restrict__ ptab, float* __restrict__ out)
{
    int bid = blockIdx.x;
    int tid = threadIdx.x;

    if (bid == NPAIR) {                 // ---- regs block: all 22 columns ----
        __shared__ int   hist[NCOL][NEMB];
        __shared__ float ssq [NCOL][NEMB];
        __shared__ float cns [NCOL];
        for (int k = tid; k < NCOL * NEMB; k += 256) ((int*)hist)[k] = 0;
        __syncthreads();
        for (int k = tid; k < NCOL * BB; k += 256) {
            int i = k >> 11;
            atomicAdd(&hist[i][features[k]], 1);
        }
        __syncthreads();
        for (int k = tid; k < NCOL * NEMB; k += 256) {
            const float* tp = tables + k * D;
            float s = 0.f;
            #pragma unroll
            for (int d = 0; d < D; ++d) s = fmaf(tp[d], tp[d], s);
            ((float*)ssq)[k] = s;
        }
        __syncthreads();
        if (tid < NCOL) {
            float s = 0.f;
            #pragma unroll
            for (int e = 0; e < NEMB; ++e)
                s += (float)hist[tid][e] * ssq[tid][e];
            cns[tid] = sqrtf(s);
        }
        __syncthreads();
        if (tid == 0) {
            float s = 0.f;
            for (int c = 0; c < NCOL; ++c) s += cns[c];
            out[BB * 2] = REGC * (2.0f * NCOL) * s;
        }
        return;
    }

    // ---- pair-table blocks ----
    int i = bid / NCOL, j = bid % NCOL;
    __shared__ float ti[NEMB][D + 1];
    __shared__ float tj[NEMB][D + 1];
    __shared__ float4 w4s[D];
    __shared__ float wl[2][D];
    __shared__ float lt[NEMB][2];

    float a0 = aw[0], a1 = aw[1], a2 = aw[2], a3 = aw[3], a4 = aw[4];
    float b2v = b2[0];

    // stage trans rows i and j (12x64 each), computed inline from tables+MLP
    for (int k = tid; k < NEMB * D; k += 256) {
        int e = k >> 6, d = k & 63;
        float x = tables[i * NEMB * D + k];
        float acc = b2v;
        #pragma unroll
        for (int h = 0; h < 8; ++h)
            acc = fmaf(tanhf(fmaf(x, w1[h], b1[h])), w2[h], acc);
        ti[e][d] = acc;
        float y = tables[j * NEMB * D + k];
        float acc2 = b2v;
        #pragma unroll
        for (int h = 0; h < 8; ++h)
            acc2 = fmaf(tanhf(fmaf(y, w1[h], b1[h])), w2[h], acc2);
        tj[e][d] = acc2;
    }

    const float* Wm   = W_ops + 1 * NPAIR * 2 * D;
    const float* Wmax = W_ops + 2 * NPAIR * 2 * D;
    const float* Wmin = W_ops + 3 * NPAIR * 2 * D;
    if (tid < D) {
        int d = tid;
        int i0 = (bid * 2 + 0) * D + d;
        int i1 = (bid * 2 + 1) * D + d;
        float4 v;
        v.x = a1 * Wm[i0];
        v.y = a1 * Wm[i1];
        v.z = 0.5f * (a2 * Wmax[i0] - a3 * Wmin[i0]);
        v.w = 0.5f * (a2 * Wmax[i1] - a3 * Wmin[i1]);
        w4s[d] = v;
    }

    // diagonal blocks also build the folded linear weight wlin[o][d]
    if (i == j && tid < 128) {
        int o = tid >> 6, d = tid & 63;
        const float* Wp = W_ops;
        float lp = 0.f, lc = 0.f, lmm = 0.f;
        #pragma unroll
        for (int jj = 0; jj < NCOL; ++jj) {
            int ij = ((i * NCOL + jj) * 2 + o) * D + d;
            int ji = ((jj * NCOL + i) * 2 + o) * D + d;
            lp += Wp[ij] + Wp[ji];
            lc += W_concat[((i * NCOL + jj) * 2 + o) * 2 * D + d]
                + W_concat[((jj * NCOL + i) * 2 + o) * 2 * D + D + d];
            lmm += a2 * (Wmax[ij] + Wmax[ji]) + a3 * (Wmin[ij] + Wmin[ji]);
        }
        wl[o][d] = a0 * lp + a4 * lc + 0.5f * lmm;
    }
    __syncthreads();

    if (i == j && tid < NEMB) {
        float l0 = 0.f, l1 = 0.f;
        #pragma unroll
        for (int d = 0; d < D; ++d) {
            float t = ti[tid][d];
            l0 = fmaf(t, wl[0][d], l0);
            l1 = fmaf(t, wl[1][d], l1);
        }
        lt[tid][0] = l0; lt[tid][1] = l1;
    }
    __syncthreads();

    if (tid < NEMB * NEMB) {
        int ei = tid / NEMB, ej = tid - ei * NEMB;
        float r0 = 0.f, r1 = 0.f;
        #pragma unroll
        for (int d = 0; d < D; ++d) {
            float a = ti[ei][d], b = tj[ej][d];
            float4 w4 = w4s[d];
            float pp = a * b;
            float dd = fabsf(a - b);
            r0 = fmaf(pp, w4.x, fmaf(dd, w4.z, r0));
            r1 = fmaf(pp, w4.y, fmaf(dd, w4.w, r1));
        }
        if (i == j && ei == ej) { r0 += lt[ei][0]; r1 += lt[ei][1]; }
        ptab[bid * 144 + tid] = make_float2(r0, r1);
    }
}

// ---------------------------------------------------------------------------
// k_gather: 256 blocks (32 b-groups x 8 pair-groups), 256 threads. lane = b,
// wave w handles pair range of global group g = pg*4+w (~15 pairs). Block
// LDS-reduces its 4 waves and writes one partial per (pg, b, o).
// ---------------------------------------------------------------------------
__global__ __launch_bounds__(256) void k_gather(const int* __restrict__ features,
        const float2* __restrict__ ptab, float* __restrict__ partial)
{
    __shared__ int fs[NCOL][64];
    __shared__ float red[4][64][2];
    int tid = threadIdx.x;
    int w = tid >> 6, lane = tid & 63;
    int bg = blockIdx.x >> 3, pg = blockIdx.x & 7;
    int b0 = bg * 64;

    for (int k = tid; k < NCOL * 64; k += 256) {
        int i = k >> 6, l = k & 63;
        fs[i][l] = features[i * BB + b0 + l];
    }
    __syncthreads();

    int g = pg * 4 + w;
    int p0 = (g * NPAIR) >> 5, p1 = ((g + 1) * NPAIR) >> 5;
    float acc0 = 0.f, acc1 = 0.f;
    #pragma unroll 4
    for (int p = p0; p < p1; ++p) {
        int i = (p * 2979) >> 16;       // exact p/22 for p < 484
        int j = p - i * NCOL;
        float2 v = ptab[p * 144 + fs[i][lane] * NEMB + fs[j][lane]];
        acc0 += v.x; acc1 += v.y;
    }
    red[w][lane][0] = acc0;
    red[w][lane][1] = acc1;
    __syncthreads();
    if (tid < 128) {
        int l = tid >> 1, o = tid & 1;
        partial[pg * (BB * 2 / 8) * 8 / 8 * 2 * 8 / 16 * 0 + pg * 4096 + (b0 + l) * 2 + o] =
            red[0][l][o] + red[1][l][o] + red[2][l][o] + red[3][l][o];
    }
}

// ---------------------------------------------------------------------------
// k_final: out[idx] = sum over 8 pair-group partials. 16 blocks x 256 = 4096.
// ---------------------------------------------------------------------------
__global__ __launch_bounds__(256) void k_final(const float* __restrict__ partial,
        float* __restrict__ out)
{
    int idx = blockIdx.x * 256 + threadIdx.x;
    float s = 0.f;
    #pragma unroll
    for (int g = 0; g < 8; ++g) s += partial[g * 4096 + idx];
    out[idx] = s;
}

extern "C" void kernel_launch(void* const* d_in, const int* in_sizes, int n_in,
                              void* d_out, int out_size, void* d_ws, size_t ws_size,
                              hipStream_t stream) {
    const int*   features = (const int*)d_in[0];
    const float* tables   = (const float*)d_in[1];
    const float* w1       = (const float*)d_in[2];
    const float* b1       = (const float*)d_in[3];
    const float* w2       = (const float*)d_in[4];
    const float* b2       = (const float*)d_in[5];
    const float* W_ops    = (const float*)d_in[6];
    const float* W_concat = (const float*)d_in[7];
    const float* aw       = (const float*)d_in[8];
    float* out = (float*)d_out;

    float2* ptab    = (float2*)d_ws;                       // 484*144*8 = 557,568 B
    float*  partial = (float*)((char*)d_ws + 557568);      // 8*4096*4  = 131,072 B

    k_ptab  <<<dim3(NPAIR + 1), dim3(256), 0, stream>>>(
        features, tables, w1, b1, w2, b2, W_ops, W_concat, aw, ptab, out);
    k_gather<<<dim3(256),       dim3(256), 0, stream>>>(features, ptab, partial);
    k_final <<<dim3(16),        dim3(256), 0, stream>>>(partial, out);
}

// Round 4
// 23.199 us; speedup vs baseline: 2.5227x; 1.4827x over previous
//
#include <hip/hip_runtime.h>
#include <math.h>

#define NCOL 22
#define NEMB 12
#define D 64
#define BB 2048
#define NPAIR (NCOL*NCOL)   // 484
#define REGC 0.001f

__device__ __forceinline__ float ftanh(float x) {
    float cx = fminf(fmaxf(x, -10.f), 10.f);
    float e = __expf(2.f * cx);
    return (e - 1.f) / (e + 1.f);
}

// ---------------------------------------------------------------------------
// k_pre: 220 blocks, four roles.
//   [0,66)    trans[i*768 + e*64 + d]  (16896 elems, one MLP eval/thread)
//   [66,187)  pw[p][d] float4 packed pair weights (30976 elems)
//   [187,198) wlin[i*128 + o*64 + d] folded linear weights (2816 elems)
//   [198,220) cn[i] column norms (22 blocks)
// ---------------------------------------------------------------------------
__global__ __launch_bounds__(256) void k_pre(
    const int* __restrict__ features, const float* __restrict__ tables,
    const float* __restrict__ w1, const float* __restrict__ b1,
    const float* __restrict__ w2, const float* __restrict__ b2,
    const float* __restrict__ W_ops, const float* __restrict__ W_concat,
    const float* __restrict__ aw,
    float* __restrict__ trans, float4* __restrict__ pw,
    float* __restrict__ wlin, float* __restrict__ cn)
{
    int bid = blockIdx.x, tid = threadIdx.x;
    const float* Wm   = W_ops + 1 * NPAIR * 2 * D;
    const float* Wmax = W_ops + 2 * NPAIR * 2 * D;
    const float* Wmin = W_ops + 3 * NPAIR * 2 * D;

    if (bid < 66) {                               // ---- trans ----
        int idx = bid * 256 + tid;
        float x = tables[idx];
        float acc = b2[0];
        #pragma unroll
        for (int h = 0; h < 8; ++h)
            acc = fmaf(ftanh(fmaf(x, w1[h], b1[h])), w2[h], acc);
        trans[idx] = acc;
    } else if (bid < 187) {                       // ---- pw pack ----
        int idx = (bid - 66) * 256 + tid;         // < 30976
        int d = idx & 63, p = idx >> 6;
        float a1 = aw[1], a2 = aw[2], a3 = aw[3];
        int i0 = (p * 2 + 0) * D + d;
        int i1 = (p * 2 + 1) * D + d;
        float4 v;
        v.x = a1 * Wm[i0];
        v.y = a1 * Wm[i1];
        v.z = 0.5f * (a2 * Wmax[i0] - a3 * Wmin[i0]);
        v.w = 0.5f * (a2 * Wmax[i1] - a3 * Wmin[i1]);
        pw[idx] = v;
    } else if (bid < 198) {                       // ---- wlin ----
        int idx = (bid - 187) * 256 + tid;        // < 2816
        int d = idx & 63; int o = (idx >> 6) & 1; int i = idx >> 7;
        float a0 = aw[0], a2 = aw[2], a3 = aw[3], a4 = aw[4];
        float lp = 0.f, lc = 0.f, lmm = 0.f;
        #pragma unroll
        for (int jj = 0; jj < NCOL; ++jj) {
            int ij = ((i * NCOL + jj) * 2 + o) * D + d;
            int ji = ((jj * NCOL + i) * 2 + o) * D + d;
            lp += W_ops[ij] + W_ops[ji];
            lc += W_concat[((i * NCOL + jj) * 2 + o) * 2 * D + d]
                + W_concat[((jj * NCOL + i) * 2 + o) * 2 * D + D + d];
            lmm += a2 * (Wmax[ij] + Wmax[ji]) + a3 * (Wmin[ij] + Wmin[ji]);
        }
        wlin[idx] = a0 * lp + a4 * lc + 0.5f * lmm;
    } else {                                      // ---- column norms ----
        int i = bid - 198;
        __shared__ float ssq[NEMB];
        __shared__ float parts[4];
        if (tid < NEMB) {
            const float* tp = tables + (i * NEMB + tid) * D;
            float s = 0.f;
            #pragma unroll
            for (int d = 0; d < D; ++d) s = fmaf(tp[d], tp[d], s);
            ssq[tid] = s;
        }
        __syncthreads();
        float s = 0.f;
        #pragma unroll
        for (int k = tid; k < BB; k += 256) s += ssq[features[i * BB + k]];
        #pragma unroll
        for (int m = 32; m; m >>= 1) s += __shfl_xor(s, m);
        if ((tid & 63) == 0) parts[tid >> 6] = s;
        __syncthreads();
        if (tid == 0)
            cn[i] = sqrtf(parts[0] + parts[1] + parts[2] + parts[3]);
    }
}

// ---------------------------------------------------------------------------
// k_ptab: 484 blocks, one per pair. Stage trans rows + packed weights, then
// 144 threads compute the (ei,ej) combo table. Diagonal folds wlin in-loop.
// ---------------------------------------------------------------------------
__global__ __launch_bounds__(256) void k_ptab(
    const float* __restrict__ trans, const float* __restrict__ wlin,
    const float4* __restrict__ pw, float2* __restrict__ ptab)
{
    int p = blockIdx.x, tid = threadIdx.x;
    int i = p / NCOL, j = p - i * NCOL;
    bool diag = (i == j);
    __shared__ float ti[NEMB * 65];
    __shared__ float tj[NEMB * 65];
    __shared__ float4 w4s[D];
    __shared__ float wls[2 * D];

    const float* tri = trans + i * NEMB * D;
    const float* trj = trans + j * NEMB * D;
    for (int k = tid; k < NEMB * D; k += 256) {
        int e = k >> 6, d = k & 63;
        ti[e * 65 + d] = tri[k];
        tj[e * 65 + d] = trj[k];
    }
    if (tid < D) w4s[tid] = pw[p * D + tid];
    if (diag && tid >= 128) wls[tid - 128] = wlin[i * 128 + (tid - 128)];
    __syncthreads();

    if (tid < NEMB * NEMB) {
        int ei = tid / NEMB, ej = tid - ei * NEMB;
        float r0 = 0.f, r1 = 0.f, l0 = 0.f, l1 = 0.f;
        #pragma unroll 8
        for (int d = 0; d < D; ++d) {
            float a = ti[ei * 65 + d], b = tj[ej * 65 + d];
            float4 w4 = w4s[d];
            float pp = a * b, dd = fabsf(a - b);
            r0 = fmaf(pp, w4.x, fmaf(dd, w4.z, r0));
            r1 = fmaf(pp, w4.y, fmaf(dd, w4.w, r1));
            if (diag & (ei == ej)) {
                l0 = fmaf(a, wls[d], l0);
                l1 = fmaf(a, wls[D + d], l1);
            }
        }
        ptab[p * 144 + tid] = make_float2(r0 + l0, r1 + l1);
    }
}

// ---------------------------------------------------------------------------
// k_gather: 256 blocks x 8 b's. Thread (g,b): g=tid>>3 sums its ~15 pairs for
// batch element b; in-block reduce over the 32 groups; writes out directly.
// Block 0 also writes the reg scalar from precomputed colnorms.
// ---------------------------------------------------------------------------
__global__ __launch_bounds__(256) void k_gather(const int* __restrict__ features,
        const float2* __restrict__ ptab, const float* __restrict__ cn,
        float* __restrict__ out)
{
    __shared__ int fs[NCOL][8];
    __shared__ float red[32][8][2];
    int tid = threadIdx.x;
    int b0 = blockIdx.x * 8;

    if (tid < NCOL * 8) {
        int i = tid >> 3, q = tid & 7;
        fs[i][q] = features[i * BB + b0 + q];
    }
    __syncthreads();

    int b = tid & 7, g = tid >> 3;
    int p0 = (g * NPAIR) >> 5, p1 = ((g + 1) * NPAIR) >> 5;
    float a0 = 0.f, a1 = 0.f;
    #pragma unroll 4
    for (int p = p0; p < p1; ++p) {
        int i = (p * 2979) >> 16;       // exact p/22 for p < 484
        int j = p - i * NCOL;
        float2 v = ptab[p * 144 + fs[i][b] * NEMB + fs[j][b]];
        a0 += v.x; a1 += v.y;
    }
    red[g][b][0] = a0;
    red[g][b][1] = a1;
    __syncthreads();
    if (tid < 16) {
        int bb = tid >> 1, o = tid & 1;
        float s = 0.f;
        #pragma unroll
        for (int g2 = 0; g2 < 32; ++g2) s += red[g2][bb][o];
        out[(b0 + bb) * 2 + o] = s;
    }
    if (blockIdx.x == 0 && tid == 64) {
        float s = 0.f;
        for (int c = 0; c < NCOL; ++c) s += cn[c];
        out[BB * 2] = REGC * (2.0f * NCOL) * s;
    }
}

extern "C" void kernel_launch(void* const* d_in, const int* in_sizes, int n_in,
                              void* d_out, int out_size, void* d_ws, size_t ws_size,
                              hipStream_t stream) {
    const int*   features = (const int*)d_in[0];
    const float* tables   = (const float*)d_in[1];
    const float* w1       = (const float*)d_in[2];
    const float* b1       = (const float*)d_in[3];
    const float* w2       = (const float*)d_in[4];
    const float* b2       = (const float*)d_in[5];
    const float* W_ops    = (const float*)d_in[6];
    const float* W_concat = (const float*)d_in[7];
    const float* aw       = (const float*)d_in[8];
    float* out = (float*)d_out;
    float* ws  = (float*)d_ws;

    float*  trans = ws;                          // 16896 f
    float*  wlin  = ws + 16896;                  // 2816 f
    float*  cn    = ws + 19712;                  // 22 f (+10 pad)
    float4* pw    = (float4*)(ws + 19744);       // 30976 f4 (16B aligned)
    float2* ptab  = (float2*)(ws + 143648);      // 484*144 f2

    k_pre   <<<dim3(220), dim3(256), 0, stream>>>(
        features, tables, w1, b1, w2, b2, W_ops, W_concat, aw,
        trans, pw, wlin, cn);
    k_ptab  <<<dim3(NPAIR), dim3(256), 0, stream>>>(trans, wlin, pw, ptab);
    k_gather<<<dim3(256),   dim3(256), 0, stream>>>(features, ptab, cn, out);
}

// Round 6
// 23.123 us; speedup vs baseline: 2.5310x; 1.0033x over previous
//
#include <hip/hip_runtime.h>
#include <math.h>

#define NCOL 22
#define NEMB 12
#define D 64
#define BB 2048
#define NPAIR (NCOL*NCOL)   // 484
#define REGC 0.001f

__device__ __forceinline__ float ftanh(float x) {
    float cx = fminf(fmaxf(x, -10.f), 10.f);
    float e = __expf(2.f * cx);
    return (e - 1.f) / (e + 1.f);
}

// ---------------------------------------------------------------------------
// k_build: blocks 0..483 — one per pair (i,j). Recompute the two trans rows
// inline (12x64 MLP evals each), pack pair weights from W_ops, diagonal
// blocks fold the linear weights, then 144 threads emit the (ei,ej) table.
// Blocks 484..505 — column norms -> cn[i].
// ---------------------------------------------------------------------------
__global__ __launch_bounds__(256) void k_build(
    const int* __restrict__ features, const float* __restrict__ tables,
    const float* __restrict__ w1, const float* __restrict__ b1,
    const float* __restrict__ w2, const float* __restrict__ b2,
    const float* __restrict__ W_ops, const float* __restrict__ W_concat,
    const float* __restrict__ aw,
    float2* __restrict__ ptab, float* __restrict__ cn)
{
    int bid = blockIdx.x, tid = threadIdx.x;

    if (bid >= NPAIR) {                 // ---- column-norm blocks ----
        int i = bid - NPAIR;
        __shared__ float ssq[NEMB];
        __shared__ float parts[4];
        if (tid < NEMB) {
            const float* tp = tables + (i * NEMB + tid) * D;
            float s = 0.f;
            #pragma unroll
            for (int d = 0; d < D; ++d) s = fmaf(tp[d], tp[d], s);
            ssq[tid] = s;
        }
        __syncthreads();
        float s = 0.f;
        for (int k = tid; k < BB; k += 256) s += ssq[features[i * BB + k]];
        #pragma unroll
        for (int m = 32; m; m >>= 1) s += __shfl_xor(s, m);
        if ((tid & 63) == 0) parts[tid >> 6] = s;
        __syncthreads();
        if (tid == 0)
            cn[i] = sqrtf(parts[0] + parts[1] + parts[2] + parts[3]);
        return;
    }

    // ---- pair blocks ----
    int i = bid / NCOL, j = bid - (bid / NCOL) * NCOL;
    bool diag = (i == j);
    __shared__ float ti[NEMB * 65];
    __shared__ float tj[NEMB * 65];
    __shared__ float4 w4s[D];
    __shared__ float wls[2 * D];

    float b2v = b2[0];
    float a0 = aw[0], a1 = aw[1], a2 = aw[2], a3 = aw[3], a4 = aw[4];
    const float* Wm   = W_ops + 1 * NPAIR * 2 * D;
    const float* Wmax = W_ops + 2 * NPAIR * 2 * D;
    const float* Wmin = W_ops + 3 * NPAIR * 2 * D;

    // stage trans rows i and j, computed inline (6 MLP evals per thread)
    for (int k = tid; k < 2 * NEMB * D; k += 256) {
        int half = (k >= NEMB * D);
        int kk = k - half * NEMB * D;
        float x = tables[(half ? j : i) * NEMB * D + kk];
        float acc = b2v;
        #pragma unroll
        for (int h = 0; h < 8; ++h)
            acc = fmaf(ftanh(fmaf(x, w1[h], b1[h])), w2[h], acc);
        (half ? tj : ti)[(kk >> 6) * 65 + (kk & 63)] = acc;
    }

    // pack pair weights (64 threads, coalesced within each array)
    if (tid < D) {
        int i0 = (bid * 2 + 0) * D + tid;
        int i1 = (bid * 2 + 1) * D + tid;
        float4 v;
        v.x = a1 * Wm[i0];
        v.y = a1 * Wm[i1];
        v.z = 0.5f * (a2 * Wmax[i0] - a3 * Wmin[i0]);
        v.w = 0.5f * (a2 * Wmax[i1] - a3 * Wmin[i1]);
        w4s[tid] = v;
    }

    // diagonal blocks fold the linear weights
    if (diag && tid >= 128 && tid < 256) {
        int t = tid - 128;
        int o = t >> 6, d = t & 63;
        float lp = 0.f, lc = 0.f, lmm = 0.f;
        #pragma unroll
        for (int jj = 0; jj < NCOL; ++jj) {
            int ij = ((i * NCOL + jj) * 2 + o) * D + d;
            int ji = ((jj * NCOL + i) * 2 + o) * D + d;
            lp += W_ops[ij] + W_ops[ji];
            lc += W_concat[((i * NCOL + jj) * 2 + o) * 2 * D + d]
                + W_concat[((jj * NCOL + i) * 2 + o) * 2 * D + D + d];
            lmm += a2 * (Wmax[ij] + Wmax[ji]) + a3 * (Wmin[ij] + Wmin[ji]);
        }
        wls[t] = a0 * lp + a4 * lc + 0.5f * lmm;
    }
    __syncthreads();

    // 144 combos
    if (tid < NEMB * NEMB) {
        int ei = tid / NEMB, ej = tid - ei * NEMB;
        float r0 = 0.f, r1 = 0.f, l0 = 0.f, l1 = 0.f;
        #pragma unroll 8
        for (int d = 0; d < D; ++d) {
            float a = ti[ei * 65 + d], b = tj[ej * 65 + d];
            float4 w4 = w4s[d];
            float pp = a * b, dd = fabsf(a - b);
            r0 = fmaf(pp, w4.x, fmaf(dd, w4.z, r0));
            r1 = fmaf(pp, w4.y, fmaf(dd, w4.w, r1));
            if (diag & (ei == ej)) {
                l0 = fmaf(a, wls[d], l0);
                l1 = fmaf(a, wls[D + d], l1);
            }
        }
        ptab[bid * 144 + tid] = make_float2(r0 + l0, r1 + l1);
    }
}

// ---------------------------------------------------------------------------
// k_gather: 256 blocks x 8 b's (round-4 passing structure — each block covers
// ALL 484 pairs; no inter-block partials). Thread (g,b): g = tid>>3 sums its
// ~15 pairs for batch element b; in-block LDS reduce over 32 groups; single
// writer per output. Block 0 also writes the reg scalar.
// ---------------------------------------------------------------------------
__global__ __launch_bounds__(256) void k_gather(const int* __restrict__ features,
        const float2* __restrict__ ptab, const float* __restrict__ cn,
        float* __restrict__ out)
{
    __shared__ int fs[NCOL][8];
    __shared__ float red[32][8][2];
    int tid = threadIdx.x;
    int b0 = blockIdx.x * 8;

    if (tid < NCOL * 8) {
        int i = tid >> 3, q = tid & 7;
        fs[i][q] = features[i * BB + b0 + q];
    }
    __syncthreads();

    int b = tid & 7, g = tid >> 3;
    int p0 = (g * NPAIR) >> 5, p1 = ((g + 1) * NPAIR) >> 5;
    float a0 = 0.f, a1 = 0.f;
    #pragma unroll 4
    for (int p = p0; p < p1; ++p) {
        int i = (p * 2979) >> 16;       // exact p/22 for p < 484
        int j = p - i * NCOL;
        float2 v = ptab[p * 144 + fs[i][b] * NEMB + fs[j][b]];
        a0 += v.x; a1 += v.y;
    }
    red[g][b][0] = a0;
    red[g][b][1] = a1;
    __syncthreads();
    if (tid < 16) {
        int bb = tid >> 1, o = tid & 1;
        float s = 0.f;
        #pragma unroll
        for (int g2 = 0; g2 < 32; ++g2) s += red[g2][bb][o];
        out[(b0 + bb) * 2 + o] = s;
    }
    if (blockIdx.x == 0 && tid == 64) {
        float s = 0.f;
        for (int c = 0; c < NCOL; ++c) s += cn[c];
        out[BB * 2] = REGC * (2.0f * NCOL) * s;
    }
}

extern "C" void kernel_launch(void* const* d_in, const int* in_sizes, int n_in,
                              void* d_out, int out_size, void* d_ws, size_t ws_size,
                              hipStream_t stream) {
    const int*   features = (const int*)d_in[0];
    const float* tables   = (const float*)d_in[1];
    const float* w1       = (const float*)d_in[2];
    const float* b1       = (const float*)d_in[3];
    const float* w2       = (const float*)d_in[4];
    const float* b2       = (const float*)d_in[5];
    const float* W_ops    = (const float*)d_in[6];
    const float* W_concat = (const float*)d_in[7];
    const float* aw       = (const float*)d_in[8];
    float* out = (float*)d_out;
    float* ws  = (float*)d_ws;

    float2* ptab = (float2*)ws;                       // 484*144 f2 = 557,568 B
    float*  cn   = ws + 2 * NPAIR * 144;              // 22 f

    k_build <<<dim3(NPAIR + NCOL), dim3(256), 0, stream>>>(
        features, tables, w1, b1, w2, b2, W_ops, W_concat, aw, ptab, cn);
    k_gather<<<dim3(256), dim3(256), 0, stream>>>(features, ptab, cn, out);
}